// Round 8
// baseline (174.218 us; speedup 1.0000x reference)
//
#include <hip/hip_runtime.h>
#include <cstdint>

// Problem: B=8, C=512, N=H*W=1024, heads=8, hd=64, groups=8.
// Contract (proven R4): inputs fp32, output fp32 (harness compares bf16-rounded).
// Round 8: (a) XOR-swizzled LDS (slot = chunk ^ (row&7)) in GEMMs + attn staging —
// keeps global_load_lds compatibility, frag reads 8-way -> 2-way bank conflicts;
// (b) GEMM BK=64 (8 K-iters, half the barrier drains); (c) attn K/V staged via
// async global_load_lds into DOUBLE-BUFFERED tiles, one barrier/iter with the
// vmcnt drain overlapped by a full iteration of compute.

typedef __bf16 bf16_t;
typedef bf16_t bf16x8 __attribute__((ext_vector_type(8)));
typedef float f32x4 __attribute__((ext_vector_type(4)));

__device__ __forceinline__ uint16_t f2bf(float f) {
  uint32_t x = __builtin_bit_cast(uint32_t, f);
  x += 0x7FFFu + ((x >> 16) & 1u);   // RNE
  return (uint16_t)(x >> 16);
}
__device__ __forceinline__ bf16x8 frag_ld(const uint16_t* p) {
  return __builtin_bit_cast(bf16x8, *(const uint4*)p);
}
__device__ __forceinline__ void gl_lds16(const uint16_t* g, uint16_t* l) {
  __builtin_amdgcn_global_load_lds(
      (const __attribute__((address_space(1))) uint32_t*)g,
      (__attribute__((address_space(3))) uint32_t*)l, 16, 0, 0);
}
#define MFMA16(a, b, c) __builtin_amdgcn_mfma_f32_16x16x32_bf16((a), (b), (c), 0, 0, 0)

// ---------------- prep: weight fp32->bf16 (bx<512) + GroupNorm stats (bx>=512) ------
__global__ __launch_bounds__(256) void prep_k(const float* __restrict__ wq,
                                              const float* __restrict__ wp,
                                              uint16_t* __restrict__ wqb,
                                              uint16_t* __restrict__ wpb,
                                              const float* __restrict__ x,
                                              float* __restrict__ stats) {
  __shared__ alignas(16) float r1[256];
  __shared__ alignas(16) float r2[256];
  int bx = blockIdx.x, t = threadIdx.x;
  if (bx < 512) {
    int idx = (bx * 256 + t) * 8;
    const float* s;
    uint16_t* d;
    if (idx < 786432) { s = wq + idx; d = wqb + idx; }
    else              { s = wp + (idx - 786432); d = wpb + (idx - 786432); }
    float4 a = *(const float4*)s;
    float4 b = *(const float4*)(s + 4);
    union { uint16_t u[8]; uint4 v; } o;
    o.u[0] = f2bf(a.x); o.u[1] = f2bf(a.y); o.u[2] = f2bf(a.z); o.u[3] = f2bf(a.w);
    o.u[4] = f2bf(b.x); o.u[5] = f2bf(b.y); o.u[6] = f2bf(b.z); o.u[7] = f2bf(b.w);
    *(uint4*)d = o.v;
    return;
  }
  int bg = bx - 512;
  const float4* p4 = (const float4*)(x + (size_t)bg * 65536);
  float s1 = 0.f, s2 = 0.f;
  for (int i = t; i < 16384; i += 256) {
    float4 u = p4[i];
    s1 += u.x + u.y + u.z + u.w;
    s2 += u.x * u.x + u.y * u.y + u.z * u.z + u.w * u.w;
  }
  r1[t] = s1; r2[t] = s2; __syncthreads();
  for (int o = 128; o > 0; o >>= 1) {
    if (t < o) { r1[t] += r1[t + o]; r2[t] += r2[t + o]; }
    __syncthreads();
  }
  if (t == 0) {
    float mu = r1[0] * (1.0f / 65536.0f);
    float var = r2[0] * (1.0f / 65536.0f) - mu * mu;
    stats[bg * 2] = mu;
    stats[bg * 2 + 1] = rsqrtf(var + 1e-5f);
  }
}

// ---------------- normalize + transpose: x fp32 (B,C,N) -> xn bf16 (B,N,C) ----------
__global__ __launch_bounds__(256) void gn_apply_k(const float* __restrict__ x,
                                                  const float* __restrict__ gamma,
                                                  const float* __restrict__ beta,
                                                  const float* __restrict__ stats,
                                                  uint16_t* __restrict__ xn) {
  int nt = blockIdx.x, g = blockIdx.y, b = blockIdx.z;
  int n0 = nt * 64;
  float mu   = stats[(b * 8 + g) * 2];
  float rstd = stats[(b * 8 + g) * 2 + 1];
  __shared__ alignas(16) uint16_t tile[64][72];
  int t = threadIdx.x;
  {
    int c_loc = t >> 2;
    int nch = (t & 3) * 16;
    int c = g * 64 + c_loc;
    float gm = gamma[c], bt = beta[c];
    const float* src = x + (size_t)b * 524288 + (size_t)c * 1024 + n0 + nch;
#pragma unroll
    for (int hh = 0; hh < 2; hh++) {
      float4 u0 = *(const float4*)(src + hh * 8);
      float4 u1 = *(const float4*)(src + hh * 8 + 4);
      union { uint16_t u16[8]; uint4 v; } o;
      o.u16[0] = f2bf((u0.x - mu) * rstd * gm + bt);
      o.u16[1] = f2bf((u0.y - mu) * rstd * gm + bt);
      o.u16[2] = f2bf((u0.z - mu) * rstd * gm + bt);
      o.u16[3] = f2bf((u0.w - mu) * rstd * gm + bt);
      o.u16[4] = f2bf((u1.x - mu) * rstd * gm + bt);
      o.u16[5] = f2bf((u1.y - mu) * rstd * gm + bt);
      o.u16[6] = f2bf((u1.z - mu) * rstd * gm + bt);
      o.u16[7] = f2bf((u1.w - mu) * rstd * gm + bt);
      *(uint4*)&tile[c_loc][nch + hh * 8] = o.v;
    }
  }
  __syncthreads();
  {
    int n_loc = t >> 2;
    int c0 = (t & 3) * 16;
    union { uint16_t u16[16]; uint4 v[2]; } o;
#pragma unroll
    for (int j = 0; j < 16; j++) o.u16[j] = tile[c0 + j][n_loc];
    uint16_t* dst = xn + (size_t)b * 524288 + (size_t)(n0 + n_loc) * 512 + g * 64 + c0;
    *(uint4*)dst = o.v[0];
    *(uint4*)(dst + 8) = o.v[1];
  }
}

// ---------------- shared 128x128 GEMM body, BK=64, XOR-swizzled LDS -----------------
// LDS tile: 128 rows x 64 k (128 B = 8 chunks/row); chunk c stored at slot c^(r&7).
// MODE 0: A=xn rows(n), B=w_qkv rows(o<1024); D[n][o] -> qtw(x1/8)/ktw via LDS transp
// MODE 1: A=w_qkv rows(1024+o'), B=xn rows(n); D[o'][n] -> vtw via LDS transpose
// MODE 2: A=w_proj rows(o), B=ot rows(n); D[o][n] + x + bias -> fp32 out (direct)
template <int MODE>
__device__ __forceinline__ void gemm_body(uint16_t* Sh,
                                          const uint16_t* Arow, const uint16_t* Brow,
                                          const float* xres, const float* biasf,
                                          uint16_t* O0, uint16_t* O1, float* Of,
                                          int b, int n0, int o0) {
  uint16_t* As = Sh;            // 128*64
  uint16_t* Bs = Sh + 8192;     // 128*64
  int t = threadIdx.x;
  int lane = t & 63, w = t >> 6;
  int qd = lane >> 4, l15 = lane & 15;
  int wm = w & 1, wn = w >> 1;

  const uint16_t* gA[4];
  const uint16_t* gB[4];
  uint16_t* lA[4];
  uint16_t* lB[4];
#pragma unroll
  for (int i = 0; i < 4; i++) {
    int p = i * 256 + t;                  // chunk position 0..1023
    int row = p >> 3, slot = p & 7, gc = slot ^ (row & 7);
    gA[i] = Arow + (size_t)row * 512 + gc * 8;
    gB[i] = Brow + (size_t)row * 512 + gc * 8;
    lA[i] = As + (size_t)(p - lane) * 8;  // wave-uniform base; HW adds lane*16
    lB[i] = Bs + (size_t)(p - lane) * 8;
  }

  f32x4 acc[4][4] = {};

  for (int k0 = 0; k0 < 512; k0 += 64) {
    __syncthreads();                      // prior iter's readers done
#pragma unroll
    for (int i = 0; i < 4; i++) { gl_lds16(gA[i] + k0, lA[i]); gl_lds16(gB[i] + k0, lB[i]); }
    __syncthreads();                      // barrier drains vmcnt

#pragma unroll
    for (int h = 0; h < 2; h++) {
      int slot = (h * 4 + qd) ^ (l15 & 7);
      bf16x8 af[4], bfr[4];
#pragma unroll
      for (int mt = 0; mt < 4; mt++)
        af[mt] = frag_ld(As + (size_t)(wm * 64 + mt * 16 + l15) * 64 + slot * 8);
#pragma unroll
      for (int nt2 = 0; nt2 < 4; nt2++)
        bfr[nt2] = frag_ld(Bs + (size_t)(wn * 64 + nt2 * 16 + l15) * 64 + slot * 8);
#pragma unroll
      for (int mt = 0; mt < 4; mt++)
#pragma unroll
        for (int nt2 = 0; nt2 < 4; nt2++)
          acc[mt][nt2] = MFMA16(af[mt], bfr[nt2], acc[mt][nt2]);
    }
  }

  if constexpr (MODE == 2) {
#pragma unroll
    for (int mt = 0; mt < 4; mt++) {
      int row = wm * 64 + mt * 16 + qd * 4;
#pragma unroll
      for (int nt2 = 0; nt2 < 4; nt2++) {
        int col = wn * 64 + nt2 * 16 + l15;
#pragma unroll
        for (int r = 0; r < 4; r++) {
          int orow = o0 + row + r, n = n0 + col;
          size_t idx = (size_t)b * 524288 + (size_t)orow * 1024 + n;
          Of[idx] = xres[idx] + biasf[orow] + acc[mt][nt2][r];
        }
      }
    }
  } else {
    // LDS-transpose epilogue -> coalesced 16B stores
    __syncthreads();                      // all waves done reading As/Bs
    uint16_t* buf = Sh + w * 1152;        // 16 x 72 per wave
    float sc = 1.0f;
    uint16_t* gbase;
    size_t rstride;
    int coff;
    if constexpr (MODE == 0) {
      int oc = o0 + wn * 64;              // 64-col band = one head
      int hh;
      uint16_t* db;
      if (oc < 512) { db = O0; hh = oc >> 6; sc = 0.125f; }   // Q pre-scale 1/8
      else          { db = O1; hh = (oc - 512) >> 6; }
      gbase = db + (size_t)(b * 8 + hh) * 65536 + (size_t)(n0 + wm * 64) * 64;
      rstride = 64;  coff = 0;
    } else {
      gbase = O0 + (size_t)b * 524288 + (size_t)(o0 + wm * 64) * 1024;
      rstride = 1024; coff = n0 + wn * 64;
    }
    int jrow = lane >> 3, joff = (lane & 7) * 8;
#pragma unroll
    for (int mt = 0; mt < 4; mt++) {
#pragma unroll
      for (int nt2 = 0; nt2 < 4; nt2++)
#pragma unroll
        for (int r = 0; r < 4; r++)
          buf[(qd * 4 + r) * 72 + nt2 * 16 + l15] = f2bf(acc[mt][nt2][r] * sc);
      // wave-private LDS: in-order within wave, no barrier
#pragma unroll
      for (int half = 0; half < 2; half++) {
        int row = jrow + half * 8;
        uint4 v = *(const uint4*)(buf + row * 72 + joff);
        *(uint4*)(gbase + (size_t)(mt * 16 + row) * rstride + coff + joff) = v;
      }
    }
  }
}

// fused QKV: blockIdx.x<8 -> Q/K tile (MODE 0), else V tile (MODE 1)
__global__ __launch_bounds__(256) void gemm01_k(const uint16_t* __restrict__ xn,
                                                const uint16_t* __restrict__ wqb,
                                                uint16_t* __restrict__ qtw,
                                                uint16_t* __restrict__ ktw,
                                                uint16_t* __restrict__ vtw) {
  __shared__ alignas(16) uint16_t Sh[16384];
  int bn = blockIdx.y;
  int b = bn >> 3, n0 = (bn & 7) * 128;
  if (blockIdx.x < 8) {
    int o0 = blockIdx.x * 128;
    gemm_body<0>(Sh, xn + (size_t)b * 524288 + (size_t)n0 * 512,
                 wqb + (size_t)o0 * 512, nullptr, nullptr, qtw, ktw, nullptr, b, n0, o0);
  } else {
    int o0 = (blockIdx.x - 8) * 128;
    gemm_body<1>(Sh, wqb + (size_t)(1024 + o0) * 512,
                 xn + (size_t)b * 524288 + (size_t)n0 * 512, nullptr, nullptr,
                 vtw, nullptr, nullptr, b, n0, o0);
  }
}

__global__ __launch_bounds__(256) void gemm2_k(const uint16_t* __restrict__ wpb,
                                               const uint16_t* __restrict__ otw,
                                               const float* __restrict__ xres,
                                               const float* __restrict__ biasf,
                                               float* __restrict__ out) {
  __shared__ alignas(16) uint16_t Sh[16384];
  int bn = blockIdx.y;
  int b = bn >> 3, n0 = (bn & 7) * 128;
  int o0 = blockIdx.x * 128;
  gemm_body<2>(Sh, wpb + (size_t)o0 * 512,
               otw + (size_t)b * 524288 + (size_t)n0 * 512, xres, biasf,
               nullptr, nullptr, out, b, n0, o0);
}

// ---------------- flash attention v5: async dbuf staging, 1 barrier/iter ------------
// 128 Q rows/block, BN=64, 16 iters. S^T = K Q^T, O^T = V^T P^T (R7 layout).
// K/V tiles (64x64, XOR-swizzled slots) staged via global_load_lds into double
// buffers; prefetch for it+1 issued at top of iter it, end-of-iter barrier's
// vmcnt drain overlapped by a full iteration of compute.
__global__ __launch_bounds__(256) void attn_k(const uint16_t* __restrict__ qt,
                                              const uint16_t* __restrict__ ktp,
                                              const uint16_t* __restrict__ vtp,
                                              uint16_t* __restrict__ ot) {
  int bh = blockIdx.x;                            // bh mod 8 -> XCD-local heads
  int b = bh >> 3, h = bh & 7;
  int n0 = blockIdx.y * 128;
  const uint16_t* qbase = qt + (size_t)bh * 65536;              // (n,d)
  const uint16_t* kbase = ktp + (size_t)bh * 65536;             // (m,d)
  const uint16_t* vbase = vtp + (size_t)b * 524288 + (size_t)h * 65536;  // (d,m)

  __shared__ alignas(16) uint16_t Ks[2][64 * 64]; // [key][d] swizzled
  __shared__ alignas(16) uint16_t Vs[2][64 * 64]; // [d][m]   swizzled
  __shared__ alignas(16) uint16_t Ps[128 * 72];   // [n][m] P^T (wave-private rows)

  int t = threadIdx.x, lane = t & 63, w = t >> 6;
  int qd = lane >> 4, l15 = lane & 15;

  bf16x8 qf[2][2];                                // B-operand frags, col n = l15
#pragma unroll
  for (int rs = 0; rs < 2; rs++) {
    const uint16_t* qp = qbase + (size_t)(n0 + w * 32 + rs * 16 + l15) * 64 + qd * 8;
    qf[rs][0] = frag_ld(qp);
    qf[rs][1] = frag_ld(qp + 32);
  }

  // staging descriptors: 2 positions per tile per thread (512 chunks each)
  int p1 = t, p2 = t + 256;
  int r1 = p1 >> 3, gc1 = (p1 & 7) ^ (r1 & 7);
  int r2 = p2 >> 3, gc2 = (p2 & 7) ^ (r2 & 7);
  const uint16_t* gK1 = kbase + (size_t)r1 * 64 + gc1 * 8;    // + m0*64 per iter
  const uint16_t* gK2 = kbase + (size_t)r2 * 64 + gc2 * 8;
  const uint16_t* gV1 = vbase + (size_t)r1 * 1024 + gc1 * 8;  // + m0 per iter
  const uint16_t* gV2 = vbase + (size_t)r2 * 1024 + gc2 * 8;
  int lo1 = (p1 - lane) * 8;                      // wave-uniform LDS offsets
  int lo2 = (p2 - lane) * 8;

  f32x4 oaccT[2][4] = {};
  float lsum[2] = {0.f, 0.f};

  // prologue: stage tile 0 -> buf 0
  gl_lds16(gK1, &Ks[0][lo1]);
  gl_lds16(gK2, &Ks[0][lo2]);
  gl_lds16(gV1, &Vs[0][lo1]);
  gl_lds16(gV2, &Vs[0][lo2]);
  __syncthreads();

  for (int it = 0; it < 16; it++) {
    int cur = it & 1, nxt = cur ^ 1;
    if (it < 15) {                                // async prefetch tile it+1
      int m0 = (it + 1) * 64;
      gl_lds16(gK1 + (size_t)m0 * 64, &Ks[nxt][lo1]);
      gl_lds16(gK2 + (size_t)m0 * 64, &Ks[nxt][lo2]);
      gl_lds16(gV1 + m0, &Vs[nxt][lo1]);
      gl_lds16(gV2 + m0, &Vs[nxt][lo2]);
    }
    const uint16_t* Kc = Ks[cur];
    const uint16_t* Vc = Vs[cur];

    // S^T = K Q^T : A=K rows m, B=Q cols n
    f32x4 sacc[2][4] = {};
#pragma unroll
    for (int mt = 0; mt < 4; mt++) {
      int row = mt * 16 + l15;
      int s0 = qd ^ (l15 & 7);
      bf16x8 kf0 = frag_ld(Kc + (size_t)row * 64 + s0 * 8);
      bf16x8 kf1 = frag_ld(Kc + (size_t)row * 64 + (s0 ^ 4) * 8);
#pragma unroll
      for (int rs = 0; rs < 2; rs++) {
        sacc[rs][mt] = MFMA16(kf0, qf[rs][0], sacc[rs][mt]);
        sacc[rs][mt] = MFMA16(kf1, qf[rs][1], sacc[rs][mt]);
      }
    }

    // p = exp(s); pack 4 consecutive keys -> one b64 store into P^T
#pragma unroll
    for (int rs = 0; rs < 2; rs++)
#pragma unroll
      for (int mt = 0; mt < 4; mt++) {
        union { uint16_t u[4]; uint2 v; } pk;
        float psum = 0.f;
#pragma unroll
        for (int r = 0; r < 4; r++) {
          float p = __expf(sacc[rs][mt][r]);
          psum += p;
          pk.u[r] = (uint16_t)(__builtin_bit_cast(uint32_t, p) >> 16);
        }
        lsum[rs] += psum;
        *(uint2*)(Ps + (size_t)(w * 32 + rs * 16 + l15) * 72 + mt * 16 + qd * 4) = pk.v;
      }

    // O^T += V^T P^T  (Ps rows wave-private: no barrier)
    bf16x8 pf[2][2];
#pragma unroll
    for (int rs = 0; rs < 2; rs++)
#pragma unroll
      for (int ks = 0; ks < 2; ks++)
        pf[rs][ks] = frag_ld(Ps + (size_t)(w * 32 + rs * 16 + l15) * 72 + ks * 32 + qd * 8);
#pragma unroll
    for (int dt = 0; dt < 4; dt++)
#pragma unroll
      for (int ks = 0; ks < 2; ks++) {
        int row = dt * 16 + l15;
        int slot = (ks * 4 + qd) ^ (l15 & 7);
        bf16x8 vf = frag_ld(Vc + (size_t)row * 64 + slot * 8);
#pragma unroll
        for (int rs = 0; rs < 2; rs++)
          oaccT[rs][dt] = MFMA16(vf, pf[rs][ks], oaccT[rs][dt]);
      }

    __syncthreads();   // all waves done with cur; drains prefetch for nxt
  }

  // epilogue: reduce lsum over qd groups, normalize, pack 4 d-values -> 8B stores
#pragma unroll
  for (int rs = 0; rs < 2; rs++) {
    float s = lsum[rs];
    s += __shfl_xor(s, 16);
    s += __shfl_xor(s, 32);
    float rinv = 1.0f / s;
    int n = n0 + w * 32 + rs * 16 + l15;
    uint16_t* orow = ot + (size_t)b * 524288 + (size_t)n * 512 + h * 64;
#pragma unroll
    for (int dt = 0; dt < 4; dt++) {
      union { uint16_t u[4]; uint2 v; } pk;
#pragma unroll
      for (int r = 0; r < 4; r++) pk.u[r] = f2bf(oaccT[rs][dt][r] * rinv);
      *(uint2*)(orow + dt * 16 + qd * 4) = pk.v;
    }
  }
}

extern "C" void kernel_launch(void* const* d_in, const int* in_sizes, int n_in,
                              void* d_out, int out_size, void* d_ws, size_t ws_size,
                              hipStream_t stream) {
  (void)in_sizes; (void)n_in; (void)out_size; (void)ws_size;
  const float* xf   = (const float*)d_in[0];
  const float* gamf = (const float*)d_in[1];
  const float* betf = (const float*)d_in[2];
  const float* wqf  = (const float*)d_in[3];
  const float* wpf  = (const float*)d_in[4];
  const float* bprf = (const float*)d_in[5];
  float* out = (float*)d_out;

  uint16_t* base = (uint16_t*)d_ws;
  float* stats   = (float*)base;           // 128 floats
  uint16_t* wqb  = base + 512;
  uint16_t* wpb  = wqb + 786432;
  uint16_t* xn   = wpb + 262144;           // (B,N,C); reused as otw after gemm01
  uint16_t* qtw  = xn  + 4194304;          // (B,H,N,hd), Q pre-scaled by 1/8
  uint16_t* ktw  = qtw + 4194304;          // (B,H,N,hd)
  uint16_t* vtw  = ktw + 4194304;          // (B, h*64+d, N)
  uint16_t* otw  = xn;

  prep_k<<<576, 256, 0, stream>>>(wqf, wpf, wqb, wpb, xf, stats);
  gn_apply_k<<<dim3(16, 8, 8), 256, 0, stream>>>(xf, gamf, betf, stats, xn);
  gemm01_k<<<dim3(12, 64), 256, 0, stream>>>(xn, wqb, qtw, ktw, vtw);
  attn_k<<<dim3(64, 8), 256, 0, stream>>>(qtw, ktw, vtw, otw);
  gemm2_k<<<dim3(4, 64), 256, 0, stream>>>(wpb, otw, xf, bprf, out);
}

// Round 9
// 168.711 us; speedup vs baseline: 1.0326x; 1.0326x over previous
//
#include <hip/hip_runtime.h>
#include <cstdint>

// Problem: B=8, C=512, N=H*W=1024, heads=8, hd=64, groups=8.
// Contract (proven R4): inputs fp32, output fp32 (harness compares bf16-rounded).
// Round 9: (a) gemm01 XCD-local grid (id&7 = n-band -> xn/wq L2-resident per XCD,
// same fix that took attn 122->12 MB FETCH in R5); (b) gemm2 XCD swizzle + async
// double-buffered K-loop (1 block/CU -> dbuf is the only latency cover there);
// (c) prep+gn_apply merged: per-(b,g) block does two-pass stats+normalize.

typedef __bf16 bf16_t;
typedef bf16_t bf16x8 __attribute__((ext_vector_type(8)));
typedef float f32x4 __attribute__((ext_vector_type(4)));

__device__ __forceinline__ uint16_t f2bf(float f) {
  uint32_t x = __builtin_bit_cast(uint32_t, f);
  x += 0x7FFFu + ((x >> 16) & 1u);   // RNE
  return (uint16_t)(x >> 16);
}
__device__ __forceinline__ bf16x8 frag_ld(const uint16_t* p) {
  return __builtin_bit_cast(bf16x8, *(const uint4*)p);
}
__device__ __forceinline__ void gl_lds16(const uint16_t* g, uint16_t* l) {
  __builtin_amdgcn_global_load_lds(
      (const __attribute__((address_space(1))) uint32_t*)g,
      (__attribute__((address_space(3))) uint32_t*)l, 16, 0, 0);
}
#define MFMA16(a, b, c) __builtin_amdgcn_mfma_f32_16x16x32_bf16((a), (b), (c), 0, 0, 0)

// ---------------- fused prep: weights fp32->bf16 (bx<512) + full GroupNorm (bx>=512)
// GN block (b,g): pass1 stats over 64ch x 1024n, pass2 normalize + transpose to
// xn(B,N,C) in 16 chunks of 64 n (re-reads hit L2).
__global__ __launch_bounds__(256) void gnfused_k(const float* __restrict__ wq,
                                                 const float* __restrict__ wp,
                                                 uint16_t* __restrict__ wqb,
                                                 uint16_t* __restrict__ wpb,
                                                 const float* __restrict__ x,
                                                 const float* __restrict__ gamma,
                                                 const float* __restrict__ beta,
                                                 uint16_t* __restrict__ xn) {
  __shared__ alignas(16) float r1[256];
  __shared__ alignas(16) float r2[256];
  __shared__ alignas(16) uint16_t tile[64][72];
  __shared__ float smu, srstd;
  int bx = blockIdx.x, t = threadIdx.x;
  if (bx < 512) {
    int idx = (bx * 256 + t) * 8;
    const float* s;
    uint16_t* d;
    if (idx < 786432) { s = wq + idx; d = wqb + idx; }
    else              { s = wp + (idx - 786432); d = wpb + (idx - 786432); }
    float4 a = *(const float4*)s;
    float4 b = *(const float4*)(s + 4);
    union { uint16_t u[8]; uint4 v; } o;
    o.u[0] = f2bf(a.x); o.u[1] = f2bf(a.y); o.u[2] = f2bf(a.z); o.u[3] = f2bf(a.w);
    o.u[4] = f2bf(b.x); o.u[5] = f2bf(b.y); o.u[6] = f2bf(b.z); o.u[7] = f2bf(b.w);
    *(uint4*)d = o.v;
    return;
  }
  int bg = bx - 512;                         // b*8+g
  int b = bg >> 3, g = bg & 7;
  const float* xbase = x + (size_t)bg * 65536;

  // pass 1: stats
  {
    const float4* p4 = (const float4*)xbase;
    float s1 = 0.f, s2 = 0.f;
    for (int i = t; i < 16384; i += 256) {
      float4 u = p4[i];
      s1 += u.x + u.y + u.z + u.w;
      s2 += u.x * u.x + u.y * u.y + u.z * u.z + u.w * u.w;
    }
    r1[t] = s1; r2[t] = s2; __syncthreads();
    for (int o = 128; o > 0; o >>= 1) {
      if (t < o) { r1[t] += r1[t + o]; r2[t] += r2[t + o]; }
      __syncthreads();
    }
    if (t == 0) {
      float mu = r1[0] * (1.0f / 65536.0f);
      float var = r2[0] * (1.0f / 65536.0f) - mu * mu;
      smu = mu; srstd = rsqrtf(var + 1e-5f);
    }
    __syncthreads();
  }
  float mu = smu, rstd = srstd;

  // pass 2: normalize + transpose, 16 chunks of 64 n
  int c_loc = t >> 2, nch = (t & 3) * 16;
  int c = g * 64 + c_loc;
  float gm = gamma[c], bt = beta[c];
  const float* srcc = xbase + (size_t)c_loc * 1024;
  int n_loc = t >> 2, c0 = (t & 3) * 16;
  uint16_t* dstc = xn + (size_t)b * 524288 + g * 64 + c0;
  for (int nt = 0; nt < 16; nt++) {
    int n0 = nt * 64;
    {
      const float* src = srcc + n0 + nch;
#pragma unroll
      for (int hh = 0; hh < 2; hh++) {
        float4 u0 = *(const float4*)(src + hh * 8);
        float4 u1 = *(const float4*)(src + hh * 8 + 4);
        union { uint16_t u16[8]; uint4 v; } o;
        o.u16[0] = f2bf((u0.x - mu) * rstd * gm + bt);
        o.u16[1] = f2bf((u0.y - mu) * rstd * gm + bt);
        o.u16[2] = f2bf((u0.z - mu) * rstd * gm + bt);
        o.u16[3] = f2bf((u0.w - mu) * rstd * gm + bt);
        o.u16[4] = f2bf((u1.x - mu) * rstd * gm + bt);
        o.u16[5] = f2bf((u1.y - mu) * rstd * gm + bt);
        o.u16[6] = f2bf((u1.z - mu) * rstd * gm + bt);
        o.u16[7] = f2bf((u1.w - mu) * rstd * gm + bt);
        *(uint4*)&tile[c_loc][nch + hh * 8] = o.v;
      }
    }
    __syncthreads();
    {
      union { uint16_t u16[16]; uint4 v[2]; } o;
#pragma unroll
      for (int j = 0; j < 16; j++) o.u16[j] = tile[c0 + j][n_loc];
      uint16_t* dst = dstc + (size_t)(n0 + n_loc) * 512;
      *(uint4*)dst = o.v[0];
      *(uint4*)(dst + 8) = o.v[1];
    }
    __syncthreads();                         // tile reused next chunk
  }
}

// ---------------- shared 128x128 GEMM body, BK=64, XOR-swizzled LDS -----------------
// MODE 0: A=xn rows(n), B=w_qkv rows(o<1024); D[n][o] -> qtw(x1/8)/ktw via LDS transp
// MODE 1: A=w_qkv rows(1024+o'), B=xn rows(n); D[o'][n] -> vtw via LDS transpose
template <int MODE>
__device__ __forceinline__ void gemm_body(uint16_t* Sh,
                                          const uint16_t* Arow, const uint16_t* Brow,
                                          uint16_t* O0, uint16_t* O1,
                                          int b, int n0, int o0) {
  uint16_t* As = Sh;            // 128*64
  uint16_t* Bs = Sh + 8192;     // 128*64
  int t = threadIdx.x;
  int lane = t & 63, w = t >> 6;
  int qd = lane >> 4, l15 = lane & 15;
  int wm = w & 1, wn = w >> 1;

  const uint16_t* gA[4];
  const uint16_t* gB[4];
  uint16_t* lA[4];
  uint16_t* lB[4];
#pragma unroll
  for (int i = 0; i < 4; i++) {
    int p = i * 256 + t;
    int row = p >> 3, slot = p & 7, gc = slot ^ (row & 7);
    gA[i] = Arow + (size_t)row * 512 + gc * 8;
    gB[i] = Brow + (size_t)row * 512 + gc * 8;
    lA[i] = As + (size_t)(p - lane) * 8;
    lB[i] = Bs + (size_t)(p - lane) * 8;
  }

  f32x4 acc[4][4] = {};

  for (int k0 = 0; k0 < 512; k0 += 64) {
    __syncthreads();
#pragma unroll
    for (int i = 0; i < 4; i++) { gl_lds16(gA[i] + k0, lA[i]); gl_lds16(gB[i] + k0, lB[i]); }
    __syncthreads();

#pragma unroll
    for (int h = 0; h < 2; h++) {
      int slot = (h * 4 + qd) ^ (l15 & 7);
      bf16x8 af[4], bfr[4];
#pragma unroll
      for (int mt = 0; mt < 4; mt++)
        af[mt] = frag_ld(As + (wm * 64 + mt * 16 + l15) * 64 + slot * 8);
#pragma unroll
      for (int nt2 = 0; nt2 < 4; nt2++)
        bfr[nt2] = frag_ld(Bs + (wn * 64 + nt2 * 16 + l15) * 64 + slot * 8);
#pragma unroll
      for (int mt = 0; mt < 4; mt++)
#pragma unroll
        for (int nt2 = 0; nt2 < 4; nt2++)
          acc[mt][nt2] = MFMA16(af[mt], bfr[nt2], acc[mt][nt2]);
    }
  }

  // LDS-transpose epilogue -> coalesced 16B stores
  __syncthreads();
  uint16_t* buf = Sh + w * 1152;        // 16 x 72 per wave
  float sc = 1.0f;
  uint16_t* gbase;
  size_t rstride;
  int coff;
  if constexpr (MODE == 0) {
    int oc = o0 + wn * 64;              // 64-col band = one head
    int hh;
    uint16_t* db;
    if (oc < 512) { db = O0; hh = oc >> 6; sc = 0.125f; }   // Q pre-scale 1/8
    else          { db = O1; hh = (oc - 512) >> 6; }
    gbase = db + (size_t)(b * 8 + hh) * 65536 + (size_t)(n0 + wm * 64) * 64;
    rstride = 64;  coff = 0;
  } else {
    gbase = O0 + (size_t)b * 524288 + (size_t)(o0 + wm * 64) * 1024;
    rstride = 1024; coff = n0 + wn * 64;
  }
  int jrow = lane >> 3, joff = (lane & 7) * 8;
#pragma unroll
  for (int mt = 0; mt < 4; mt++) {
#pragma unroll
    for (int nt2 = 0; nt2 < 4; nt2++)
#pragma unroll
      for (int r = 0; r < 4; r++)
        buf[(qd * 4 + r) * 72 + nt2 * 16 + l15] = f2bf(acc[mt][nt2][r] * sc);
#pragma unroll
    for (int half = 0; half < 2; half++) {
      int row = jrow + half * 8;
      uint4 v = *(const uint4*)(buf + row * 72 + joff);
      *(uint4*)(gbase + (size_t)(mt * 16 + row) * rstride + coff + joff) = v;
    }
  }
}

// fused QKV, XCD-local 1D grid: id&7 = n-band (each XCD owns one n-band; xn bands
// + wq stay L2-resident). hi%12 picks the o-tile/mode, hi/12 the batch.
__global__ __launch_bounds__(256) void gemm01_k(const uint16_t* __restrict__ xn,
                                                const uint16_t* __restrict__ wqb,
                                                uint16_t* __restrict__ qtw,
                                                uint16_t* __restrict__ ktw,
                                                uint16_t* __restrict__ vtw) {
  __shared__ alignas(16) uint16_t Sh[16384];
  int id = blockIdx.x;                  // 768
  int lo = id & 7, hi = id >> 3;        // hi 0..95
  int o12 = hi % 12, b = hi / 12;       // b 0..7
  int n0 = lo * 128;
  if (o12 < 8) {
    int o0 = o12 * 128;
    gemm_body<0>(Sh, xn + (size_t)b * 524288 + (size_t)n0 * 512,
                 wqb + (size_t)o0 * 512, qtw, ktw, b, n0, o0);
  } else {
    int o0 = (o12 - 8) * 128;
    gemm_body<1>(Sh, wqb + (size_t)(1024 + o0) * 512,
                 xn + (size_t)b * 524288 + (size_t)n0 * 512, vtw, nullptr, b, n0, o0);
  }
}

// proj GEMM: XCD swizzle + async double-buffered BK=64 (1 block/CU -> dbuf is the
// only latency cover). D[o][n] + x + bias -> fp32 out.
__global__ __launch_bounds__(256) void gemm2_k(const uint16_t* __restrict__ wpb,
                                               const uint16_t* __restrict__ otw,
                                               const float* __restrict__ xres,
                                               const float* __restrict__ biasf,
                                               float* __restrict__ out) {
  __shared__ alignas(16) uint16_t As[2][8192];
  __shared__ alignas(16) uint16_t Bs[2][8192];
  int id = blockIdx.x;                  // 256
  int lo = id & 7, hi = id >> 3;        // hi 0..31
  int o0 = (hi & 3) * 128, b = hi >> 2, n0 = lo * 128;
  const uint16_t* Arow = wpb + (size_t)o0 * 512;
  const uint16_t* Brow = otw + (size_t)b * 524288 + (size_t)n0 * 512;

  int t = threadIdx.x, lane = t & 63, w = t >> 6;
  int qd = lane >> 4, l15 = lane & 15;
  int wm = w & 1, wn = w >> 1;

  const uint16_t* gA[4];
  const uint16_t* gB[4];
  int lofs[4];
#pragma unroll
  for (int i = 0; i < 4; i++) {
    int p = i * 256 + t;
    int row = p >> 3, slot = p & 7, gc = slot ^ (row & 7);
    gA[i] = Arow + (size_t)row * 512 + gc * 8;
    gB[i] = Brow + (size_t)row * 512 + gc * 8;
    lofs[i] = (p - lane) * 8;
  }

  f32x4 acc[4][4] = {};
#pragma unroll
  for (int i = 0; i < 4; i++) { gl_lds16(gA[i], &As[0][lofs[i]]); gl_lds16(gB[i], &Bs[0][lofs[i]]); }
  __syncthreads();

  for (int kt = 0; kt < 8; kt++) {
    int cur = kt & 1, nxt = cur ^ 1;
    if (kt < 7) {
      int k0 = (kt + 1) * 64;
#pragma unroll
      for (int i = 0; i < 4; i++) { gl_lds16(gA[i] + k0, &As[nxt][lofs[i]]); gl_lds16(gB[i] + k0, &Bs[nxt][lofs[i]]); }
    }
#pragma unroll
    for (int h = 0; h < 2; h++) {
      int slot = (h * 4 + qd) ^ (l15 & 7);
      bf16x8 af[4], bfr[4];
#pragma unroll
      for (int mt = 0; mt < 4; mt++)
        af[mt] = frag_ld(&As[cur][(wm * 64 + mt * 16 + l15) * 64 + slot * 8]);
#pragma unroll
      for (int nt2 = 0; nt2 < 4; nt2++)
        bfr[nt2] = frag_ld(&Bs[cur][(wn * 64 + nt2 * 16 + l15) * 64 + slot * 8]);
#pragma unroll
      for (int mt = 0; mt < 4; mt++)
#pragma unroll
        for (int nt2 = 0; nt2 < 4; nt2++)
          acc[mt][nt2] = MFMA16(af[mt], bfr[nt2], acc[mt][nt2]);
    }
    __syncthreads();   // readers done with cur; drains prefetch into nxt
  }

#pragma unroll
  for (int mt = 0; mt < 4; mt++) {
    int row = wm * 64 + mt * 16 + qd * 4;
#pragma unroll
    for (int nt2 = 0; nt2 < 4; nt2++) {
      int col = wn * 64 + nt2 * 16 + l15;
#pragma unroll
      for (int r = 0; r < 4; r++) {
        int orow = o0 + row + r, n = n0 + col;
        size_t idx = (size_t)b * 524288 + (size_t)orow * 1024 + n;
        out[idx] = xres[idx] + biasf[orow] + acc[mt][nt2][r];
      }
    }
  }
}

// ---------------- flash attention v5 (R8): async dbuf staging, 1 barrier/iter -------
__global__ __launch_bounds__(256) void attn_k(const uint16_t* __restrict__ qt,
                                              const uint16_t* __restrict__ ktp,
                                              const uint16_t* __restrict__ vtp,
                                              uint16_t* __restrict__ ot) {
  int bh = blockIdx.x;                            // bh mod 8 -> XCD-local heads
  int b = bh >> 3, h = bh & 7;
  int n0 = blockIdx.y * 128;
  const uint16_t* qbase = qt + (size_t)bh * 65536;              // (n,d)
  const uint16_t* kbase = ktp + (size_t)bh * 65536;             // (m,d)
  const uint16_t* vbase = vtp + (size_t)b * 524288 + (size_t)h * 65536;  // (d,m)

  __shared__ alignas(16) uint16_t Ks[2][64 * 64];
  __shared__ alignas(16) uint16_t Vs[2][64 * 64];
  __shared__ alignas(16) uint16_t Ps[128 * 72];

  int t = threadIdx.x, lane = t & 63, w = t >> 6;
  int qd = lane >> 4, l15 = lane & 15;

  bf16x8 qf[2][2];
#pragma unroll
  for (int rs = 0; rs < 2; rs++) {
    const uint16_t* qp = qbase + (size_t)(n0 + w * 32 + rs * 16 + l15) * 64 + qd * 8;
    qf[rs][0] = frag_ld(qp);
    qf[rs][1] = frag_ld(qp + 32);
  }

  int p1 = t, p2 = t + 256;
  int r1 = p1 >> 3, gc1 = (p1 & 7) ^ (r1 & 7);
  int r2 = p2 >> 3, gc2 = (p2 & 7) ^ (r2 & 7);
  const uint16_t* gK1 = kbase + (size_t)r1 * 64 + gc1 * 8;
  const uint16_t* gK2 = kbase + (size_t)r2 * 64 + gc2 * 8;
  const uint16_t* gV1 = vbase + (size_t)r1 * 1024 + gc1 * 8;
  const uint16_t* gV2 = vbase + (size_t)r2 * 1024 + gc2 * 8;
  int lo1 = (p1 - lane) * 8;
  int lo2 = (p2 - lane) * 8;

  f32x4 oaccT[2][4] = {};
  float lsum[2] = {0.f, 0.f};

  gl_lds16(gK1, &Ks[0][lo1]);
  gl_lds16(gK2, &Ks[0][lo2]);
  gl_lds16(gV1, &Vs[0][lo1]);
  gl_lds16(gV2, &Vs[0][lo2]);
  __syncthreads();

  for (int it = 0; it < 16; it++) {
    int cur = it & 1, nxt = cur ^ 1;
    if (it < 15) {
      int m0 = (it + 1) * 64;
      gl_lds16(gK1 + (size_t)m0 * 64, &Ks[nxt][lo1]);
      gl_lds16(gK2 + (size_t)m0 * 64, &Ks[nxt][lo2]);
      gl_lds16(gV1 + m0, &Vs[nxt][lo1]);
      gl_lds16(gV2 + m0, &Vs[nxt][lo2]);
    }
    const uint16_t* Kc = Ks[cur];
    const uint16_t* Vc = Vs[cur];

    f32x4 sacc[2][4] = {};
#pragma unroll
    for (int mt = 0; mt < 4; mt++) {
      int row = mt * 16 + l15;
      int s0 = qd ^ (l15 & 7);
      bf16x8 kf0 = frag_ld(Kc + (size_t)row * 64 + s0 * 8);
      bf16x8 kf1 = frag_ld(Kc + (size_t)row * 64 + (s0 ^ 4) * 8);
#pragma unroll
      for (int rs = 0; rs < 2; rs++) {
        sacc[rs][mt] = MFMA16(kf0, qf[rs][0], sacc[rs][mt]);
        sacc[rs][mt] = MFMA16(kf1, qf[rs][1], sacc[rs][mt]);
      }
    }

#pragma unroll
    for (int rs = 0; rs < 2; rs++)
#pragma unroll
      for (int mt = 0; mt < 4; mt++) {
        union { uint16_t u[4]; uint2 v; } pk;
        float psum = 0.f;
#pragma unroll
        for (int r = 0; r < 4; r++) {
          float p = __expf(sacc[rs][mt][r]);
          psum += p;
          pk.u[r] = (uint16_t)(__builtin_bit_cast(uint32_t, p) >> 16);
        }
        lsum[rs] += psum;
        *(uint2*)(Ps + (size_t)(w * 32 + rs * 16 + l15) * 72 + mt * 16 + qd * 4) = pk.v;
      }

    bf16x8 pf[2][2];
#pragma unroll
    for (int rs = 0; rs < 2; rs++)
#pragma unroll
      for (int ks = 0; ks < 2; ks++)
        pf[rs][ks] = frag_ld(Ps + (size_t)(w * 32 + rs * 16 + l15) * 72 + ks * 32 + qd * 8);
#pragma unroll
    for (int dt = 0; dt < 4; dt++)
#pragma unroll
      for (int ks = 0; ks < 2; ks++) {
        int row = dt * 16 + l15;
        int slot = (ks * 4 + qd) ^ (l15 & 7);
        bf16x8 vf = frag_ld(Vc + (size_t)row * 64 + slot * 8);
#pragma unroll
        for (int rs = 0; rs < 2; rs++)
          oaccT[rs][dt] = MFMA16(vf, pf[rs][ks], oaccT[rs][dt]);
      }

    __syncthreads();
  }

#pragma unroll
  for (int rs = 0; rs < 2; rs++) {
    float s = lsum[rs];
    s += __shfl_xor(s, 16);
    s += __shfl_xor(s, 32);
    float rinv = 1.0f / s;
    int n = n0 + w * 32 + rs * 16 + l15;
    uint16_t* orow = ot + (size_t)b * 524288 + (size_t)n * 512 + h * 64;
#pragma unroll
    for (int dt = 0; dt < 4; dt++) {
      union { uint16_t u[4]; uint2 v; } pk;
#pragma unroll
      for (int r = 0; r < 4; r++) pk.u[r] = f2bf(oaccT[rs][dt][r] * rinv);
      *(uint2*)(orow + dt * 16 + qd * 4) = pk.v;
    }
  }
}

extern "C" void kernel_launch(void* const* d_in, const int* in_sizes, int n_in,
                              void* d_out, int out_size, void* d_ws, size_t ws_size,
                              hipStream_t stream) {
  (void)in_sizes; (void)n_in; (void)out_size; (void)ws_size;
  const float* xf   = (const float*)d_in[0];
  const float* gamf = (const float*)d_in[1];
  const float* betf = (const float*)d_in[2];
  const float* wqf  = (const float*)d_in[3];
  const float* wpf  = (const float*)d_in[4];
  const float* bprf = (const float*)d_in[5];
  float* out = (float*)d_out;

  uint16_t* base = (uint16_t*)d_ws;
  uint16_t* wqb  = base;
  uint16_t* wpb  = wqb + 786432;
  uint16_t* xn   = wpb + 262144;           // (B,N,C); reused as otw after gemm01
  uint16_t* qtw  = xn  + 4194304;          // (B,H,N,hd), Q pre-scaled by 1/8
  uint16_t* ktw  = qtw + 4194304;          // (B,H,N,hd)
  uint16_t* vtw  = ktw + 4194304;          // (B, h*64+d, N)
  uint16_t* otw  = xn;

  gnfused_k<<<576, 256, 0, stream>>>(wqf, wpf, wqb, wpb, xf, gamf, betf, xn);
  gemm01_k<<<768, 256, 0, stream>>>(xn, wqb, qtw, ktw, vtw);
  attn_k<<<dim3(64, 8), 256, 0, stream>>>(qtw, ktw, vtw, otw);
  gemm2_k<<<256, 256, 0, stream>>>(wpb, otw, xf, bprf, out);
}

// Round 10
// 147.672 us; speedup vs baseline: 1.1798x; 1.1425x over previous
//
#include <hip/hip_runtime.h>
#include <cstdint>

// Problem: B=8, C=512, H=W=32 -> N=1024, heads=8, hd=64, groups=8.
// Contract (proven R4): inputs fp32, output fp32 (harness compares bf16-rounded).
// Round 10: un-fuse GN (R9's gnfused serialized to 64 blocks = 50 µs, occupancy
// 2.6%). prep_k = weight conv (512 blk) + 4-way partial GN stats (256 blk, no
// atomics); gn_apply_k (1024 blk) reduces the 4 partials. gemm01/attn/gemm2
// unchanged from R9 (XCD-local grids were the R9 win: ~44 µs off).

typedef __bf16 bf16_t;
typedef bf16_t bf16x8 __attribute__((ext_vector_type(8)));
typedef float f32x4 __attribute__((ext_vector_type(4)));

__device__ __forceinline__ uint16_t f2bf(float f) {
  uint32_t x = __builtin_bit_cast(uint32_t, f);
  x += 0x7FFFu + ((x >> 16) & 1u);   // RNE
  return (uint16_t)(x >> 16);
}
__device__ __forceinline__ bf16x8 frag_ld(const uint16_t* p) {
  return __builtin_bit_cast(bf16x8, *(const uint4*)p);
}
__device__ __forceinline__ void gl_lds16(const uint16_t* g, uint16_t* l) {
  __builtin_amdgcn_global_load_lds(
      (const __attribute__((address_space(1))) uint32_t*)g,
      (__attribute__((address_space(3))) uint32_t*)l, 16, 0, 0);
}
#define MFMA16(a, b, c) __builtin_amdgcn_mfma_f32_16x16x32_bf16((a), (b), (c), 0, 0, 0)

// ---------------- prep: weight fp32->bf16 (bx<512) + partial GN stats (bx>=512) -----
// Stats blocks: 4 per (b,g), each reduces 16384 floats -> (s1,s2) into its own slot.
__global__ __launch_bounds__(256) void prep_k(const float* __restrict__ wq,
                                              const float* __restrict__ wp,
                                              uint16_t* __restrict__ wqb,
                                              uint16_t* __restrict__ wpb,
                                              const float* __restrict__ x,
                                              float* __restrict__ stats) {
  __shared__ alignas(16) float r1[256];
  __shared__ alignas(16) float r2[256];
  int bx = blockIdx.x, t = threadIdx.x;
  if (bx < 512) {
    int idx = (bx * 256 + t) * 8;
    const float* s;
    uint16_t* d;
    if (idx < 786432) { s = wq + idx; d = wqb + idx; }
    else              { s = wp + (idx - 786432); d = wpb + (idx - 786432); }
    float4 a = *(const float4*)s;
    float4 b = *(const float4*)(s + 4);
    union { uint16_t u[8]; uint4 v; } o;
    o.u[0] = f2bf(a.x); o.u[1] = f2bf(a.y); o.u[2] = f2bf(a.z); o.u[3] = f2bf(a.w);
    o.u[4] = f2bf(b.x); o.u[5] = f2bf(b.y); o.u[6] = f2bf(b.z); o.u[7] = f2bf(b.w);
    *(uint4*)d = o.v;
    return;
  }
  int pg = bx - 512;                         // 0..255: (b*8+g)*4 + part
  const float4* p4 = (const float4*)(x + (size_t)(pg >> 2) * 65536 + (pg & 3) * 16384);
  float s1 = 0.f, s2 = 0.f;
  for (int i = t; i < 4096; i += 256) {
    float4 u = p4[i];
    s1 += u.x + u.y + u.z + u.w;
    s2 += u.x * u.x + u.y * u.y + u.z * u.z + u.w * u.w;
  }
  r1[t] = s1; r2[t] = s2; __syncthreads();
  for (int o = 128; o > 0; o >>= 1) {
    if (t < o) { r1[t] += r1[t + o]; r2[t] += r2[t + o]; }
    __syncthreads();
  }
  if (t == 0) { stats[pg * 2] = r1[0]; stats[pg * 2 + 1] = r2[0]; }
}

// ---------------- normalize + transpose: x fp32 (B,C,N) -> xn bf16 (B,N,C) ----------
__global__ __launch_bounds__(256) void gn_apply_k(const float* __restrict__ x,
                                                  const float* __restrict__ gamma,
                                                  const float* __restrict__ beta,
                                                  const float* __restrict__ stats,
                                                  uint16_t* __restrict__ xn) {
  int nt = blockIdx.x, g = blockIdx.y, b = blockIdx.z;
  int n0 = nt * 64;
  int bg = b * 8 + g;
  float s1 = 0.f, s2 = 0.f;
#pragma unroll
  for (int p = 0; p < 4; p++) { s1 += stats[(bg * 4 + p) * 2]; s2 += stats[(bg * 4 + p) * 2 + 1]; }
  float mu   = s1 * (1.0f / 65536.0f);
  float var  = s2 * (1.0f / 65536.0f) - mu * mu;
  float rstd = rsqrtf(var + 1e-5f);
  __shared__ alignas(16) uint16_t tile[64][72];
  int t = threadIdx.x;
  {
    int c_loc = t >> 2;
    int nch = (t & 3) * 16;
    int c = g * 64 + c_loc;
    float gm = gamma[c], bt = beta[c];
    const float* src = x + (size_t)b * 524288 + (size_t)c * 1024 + n0 + nch;
#pragma unroll
    for (int hh = 0; hh < 2; hh++) {
      float4 u0 = *(const float4*)(src + hh * 8);
      float4 u1 = *(const float4*)(src + hh * 8 + 4);
      union { uint16_t u16[8]; uint4 v; } o;
      o.u16[0] = f2bf((u0.x - mu) * rstd * gm + bt);
      o.u16[1] = f2bf((u0.y - mu) * rstd * gm + bt);
      o.u16[2] = f2bf((u0.z - mu) * rstd * gm + bt);
      o.u16[3] = f2bf((u0.w - mu) * rstd * gm + bt);
      o.u16[4] = f2bf((u1.x - mu) * rstd * gm + bt);
      o.u16[5] = f2bf((u1.y - mu) * rstd * gm + bt);
      o.u16[6] = f2bf((u1.z - mu) * rstd * gm + bt);
      o.u16[7] = f2bf((u1.w - mu) * rstd * gm + bt);
      *(uint4*)&tile[c_loc][nch + hh * 8] = o.v;
    }
  }
  __syncthreads();
  {
    int n_loc = t >> 2;
    int c0 = (t & 3) * 16;
    union { uint16_t u16[16]; uint4 v[2]; } o;
#pragma unroll
    for (int j = 0; j < 16; j++) o.u16[j] = tile[c0 + j][n_loc];
    uint16_t* dst = xn + (size_t)b * 524288 + (size_t)(n0 + n_loc) * 512 + g * 64 + c0;
    *(uint4*)dst = o.v[0];
    *(uint4*)(dst + 8) = o.v[1];
  }
}

// ---------------- shared 128x128 GEMM body, BK=64, XOR-swizzled LDS -----------------
// MODE 0: A=xn rows(n), B=w_qkv rows(o<1024); D[n][o] -> qtw(x1/8)/ktw via LDS transp
// MODE 1: A=w_qkv rows(1024+o'), B=xn rows(n); D[o'][n] -> vtw via LDS transpose
template <int MODE>
__device__ __forceinline__ void gemm_body(uint16_t* Sh,
                                          const uint16_t* Arow, const uint16_t* Brow,
                                          uint16_t* O0, uint16_t* O1,
                                          int b, int n0, int o0) {
  uint16_t* As = Sh;            // 128*64
  uint16_t* Bs = Sh + 8192;     // 128*64
  int t = threadIdx.x;
  int lane = t & 63, w = t >> 6;
  int qd = lane >> 4, l15 = lane & 15;
  int wm = w & 1, wn = w >> 1;

  const uint16_t* gA[4];
  const uint16_t* gB[4];
  uint16_t* lA[4];
  uint16_t* lB[4];
#pragma unroll
  for (int i = 0; i < 4; i++) {
    int p = i * 256 + t;
    int row = p >> 3, slot = p & 7, gc = slot ^ (row & 7);
    gA[i] = Arow + (size_t)row * 512 + gc * 8;
    gB[i] = Brow + (size_t)row * 512 + gc * 8;
    lA[i] = As + (size_t)(p - lane) * 8;
    lB[i] = Bs + (size_t)(p - lane) * 8;
  }

  f32x4 acc[4][4] = {};

  for (int k0 = 0; k0 < 512; k0 += 64) {
    __syncthreads();
#pragma unroll
    for (int i = 0; i < 4; i++) { gl_lds16(gA[i] + k0, lA[i]); gl_lds16(gB[i] + k0, lB[i]); }
    __syncthreads();

#pragma unroll
    for (int h = 0; h < 2; h++) {
      int slot = (h * 4 + qd) ^ (l15 & 7);
      bf16x8 af[4], bfr[4];
#pragma unroll
      for (int mt = 0; mt < 4; mt++)
        af[mt] = frag_ld(As + (wm * 64 + mt * 16 + l15) * 64 + slot * 8);
#pragma unroll
      for (int nt2 = 0; nt2 < 4; nt2++)
        bfr[nt2] = frag_ld(Bs + (wn * 64 + nt2 * 16 + l15) * 64 + slot * 8);
#pragma unroll
      for (int mt = 0; mt < 4; mt++)
#pragma unroll
        for (int nt2 = 0; nt2 < 4; nt2++)
          acc[mt][nt2] = MFMA16(af[mt], bfr[nt2], acc[mt][nt2]);
    }
  }

  // LDS-transpose epilogue -> coalesced 16B stores
  __syncthreads();
  uint16_t* buf = Sh + w * 1152;        // 16 x 72 per wave
  float sc = 1.0f;
  uint16_t* gbase;
  size_t rstride;
  int coff;
  if constexpr (MODE == 0) {
    int oc = o0 + wn * 64;              // 64-col band = one head
    int hh;
    uint16_t* db;
    if (oc < 512) { db = O0; hh = oc >> 6; sc = 0.125f; }   // Q pre-scale 1/8
    else          { db = O1; hh = (oc - 512) >> 6; }
    gbase = db + (size_t)(b * 8 + hh) * 65536 + (size_t)(n0 + wm * 64) * 64;
    rstride = 64;  coff = 0;
  } else {
    gbase = O0 + (size_t)b * 524288 + (size_t)(o0 + wm * 64) * 1024;
    rstride = 1024; coff = n0 + wn * 64;
  }
  int jrow = lane >> 3, joff = (lane & 7) * 8;
#pragma unroll
  for (int mt = 0; mt < 4; mt++) {
#pragma unroll
    for (int nt2 = 0; nt2 < 4; nt2++)
#pragma unroll
      for (int r = 0; r < 4; r++)
        buf[(qd * 4 + r) * 72 + nt2 * 16 + l15] = f2bf(acc[mt][nt2][r] * sc);
#pragma unroll
    for (int half = 0; half < 2; half++) {
      int row = jrow + half * 8;
      uint4 v = *(const uint4*)(buf + row * 72 + joff);
      *(uint4*)(gbase + (size_t)(mt * 16 + row) * rstride + coff + joff) = v;
    }
  }
}

// fused QKV, XCD-local 1D grid: id&7 = n-band (xn bands + wq L2-resident per XCD)
__global__ __launch_bounds__(256) void gemm01_k(const uint16_t* __restrict__ xn,
                                                const uint16_t* __restrict__ wqb,
                                                uint16_t* __restrict__ qtw,
                                                uint16_t* __restrict__ ktw,
                                                uint16_t* __restrict__ vtw) {
  __shared__ alignas(16) uint16_t Sh[16384];
  int id = blockIdx.x;                  // 768
  int lo = id & 7, hi = id >> 3;        // hi 0..95
  int o12 = hi % 12, b = hi / 12;       // b 0..7
  int n0 = lo * 128;
  if (o12 < 8) {
    int o0 = o12 * 128;
    gemm_body<0>(Sh, xn + (size_t)b * 524288 + (size_t)n0 * 512,
                 wqb + (size_t)o0 * 512, qtw, ktw, b, n0, o0);
  } else {
    int o0 = (o12 - 8) * 128;
    gemm_body<1>(Sh, wqb + (size_t)(1024 + o0) * 512,
                 xn + (size_t)b * 524288 + (size_t)n0 * 512, vtw, nullptr, b, n0, o0);
  }
}

// proj GEMM: XCD swizzle + async double-buffered BK=64 -> fp32 out (+x, +bias)
__global__ __launch_bounds__(256) void gemm2_k(const uint16_t* __restrict__ wpb,
                                               const uint16_t* __restrict__ otw,
                                               const float* __restrict__ xres,
                                               const float* __restrict__ biasf,
                                               float* __restrict__ out) {
  __shared__ alignas(16) uint16_t As[2][8192];
  __shared__ alignas(16) uint16_t Bs[2][8192];
  int id = blockIdx.x;                  // 256
  int lo = id & 7, hi = id >> 3;        // hi 0..31
  int o0 = (hi & 3) * 128, b = hi >> 2, n0 = lo * 128;
  const uint16_t* Arow = wpb + (size_t)o0 * 512;
  const uint16_t* Brow = otw + (size_t)b * 524288 + (size_t)n0 * 512;

  int t = threadIdx.x, lane = t & 63, w = t >> 6;
  int qd = lane >> 4, l15 = lane & 15;
  int wm = w & 1, wn = w >> 1;

  const uint16_t* gA[4];
  const uint16_t* gB[4];
  int lofs[4];
#pragma unroll
  for (int i = 0; i < 4; i++) {
    int p = i * 256 + t;
    int row = p >> 3, slot = p & 7, gc = slot ^ (row & 7);
    gA[i] = Arow + (size_t)row * 512 + gc * 8;
    gB[i] = Brow + (size_t)row * 512 + gc * 8;
    lofs[i] = (p - lane) * 8;
  }

  f32x4 acc[4][4] = {};
#pragma unroll
  for (int i = 0; i < 4; i++) { gl_lds16(gA[i], &As[0][lofs[i]]); gl_lds16(gB[i], &Bs[0][lofs[i]]); }
  __syncthreads();

  for (int kt = 0; kt < 8; kt++) {
    int cur = kt & 1, nxt = cur ^ 1;
    if (kt < 7) {
      int k0 = (kt + 1) * 64;
#pragma unroll
      for (int i = 0; i < 4; i++) { gl_lds16(gA[i] + k0, &As[nxt][lofs[i]]); gl_lds16(gB[i] + k0, &Bs[nxt][lofs[i]]); }
    }
#pragma unroll
    for (int h = 0; h < 2; h++) {
      int slot = (h * 4 + qd) ^ (l15 & 7);
      bf16x8 af[4], bfr[4];
#pragma unroll
      for (int mt = 0; mt < 4; mt++)
        af[mt] = frag_ld(&As[cur][(wm * 64 + mt * 16 + l15) * 64 + slot * 8]);
#pragma unroll
      for (int nt2 = 0; nt2 < 4; nt2++)
        bfr[nt2] = frag_ld(&Bs[cur][(wn * 64 + nt2 * 16 + l15) * 64 + slot * 8]);
#pragma unroll
      for (int mt = 0; mt < 4; mt++)
#pragma unroll
        for (int nt2 = 0; nt2 < 4; nt2++)
          acc[mt][nt2] = MFMA16(af[mt], bfr[nt2], acc[mt][nt2]);
    }
    __syncthreads();   // readers done with cur; drains prefetch into nxt
  }

#pragma unroll
  for (int mt = 0; mt < 4; mt++) {
    int row = wm * 64 + mt * 16 + qd * 4;
#pragma unroll
    for (int nt2 = 0; nt2 < 4; nt2++) {
      int col = wn * 64 + nt2 * 16 + l15;
#pragma unroll
      for (int r = 0; r < 4; r++) {
        int orow = o0 + row + r, n = n0 + col;
        size_t idx = (size_t)b * 524288 + (size_t)orow * 1024 + n;
        out[idx] = xres[idx] + biasf[orow] + acc[mt][nt2][r];
      }
    }
  }
}

// ---------------- flash attention v5: async dbuf staging, 1 barrier/iter ------------
__global__ __launch_bounds__(256) void attn_k(const uint16_t* __restrict__ qt,
                                              const uint16_t* __restrict__ ktp,
                                              const uint16_t* __restrict__ vtp,
                                              uint16_t* __restrict__ ot) {
  int bh = blockIdx.x;                            // bh mod 8 -> XCD-local heads
  int b = bh >> 3, h = bh & 7;
  int n0 = blockIdx.y * 128;
  const uint16_t* qbase = qt + (size_t)bh * 65536;              // (n,d)
  const uint16_t* kbase = ktp + (size_t)bh * 65536;             // (m,d)
  const uint16_t* vbase = vtp + (size_t)b * 524288 + (size_t)h * 65536;  // (d,m)

  __shared__ alignas(16) uint16_t Ks[2][64 * 64];
  __shared__ alignas(16) uint16_t Vs[2][64 * 64];
  __shared__ alignas(16) uint16_t Ps[128 * 72];

  int t = threadIdx.x, lane = t & 63, w = t >> 6;
  int qd = lane >> 4, l15 = lane & 15;

  bf16x8 qf[2][2];
#pragma unroll
  for (int rs = 0; rs < 2; rs++) {
    const uint16_t* qp = qbase + (size_t)(n0 + w * 32 + rs * 16 + l15) * 64 + qd * 8;
    qf[rs][0] = frag_ld(qp);
    qf[rs][1] = frag_ld(qp + 32);
  }

  int p1 = t, p2 = t + 256;
  int r1 = p1 >> 3, gc1 = (p1 & 7) ^ (r1 & 7);
  int r2 = p2 >> 3, gc2 = (p2 & 7) ^ (r2 & 7);
  const uint16_t* gK1 = kbase + (size_t)r1 * 64 + gc1 * 8;
  const uint16_t* gK2 = kbase + (size_t)r2 * 64 + gc2 * 8;
  const uint16_t* gV1 = vbase + (size_t)r1 * 1024 + gc1 * 8;
  const uint16_t* gV2 = vbase + (size_t)r2 * 1024 + gc2 * 8;
  int lo1 = (p1 - lane) * 8;
  int lo2 = (p2 - lane) * 8;

  f32x4 oaccT[2][4] = {};
  float lsum[2] = {0.f, 0.f};

  gl_lds16(gK1, &Ks[0][lo1]);
  gl_lds16(gK2, &Ks[0][lo2]);
  gl_lds16(gV1, &Vs[0][lo1]);
  gl_lds16(gV2, &Vs[0][lo2]);
  __syncthreads();

  for (int it = 0; it < 16; it++) {
    int cur = it & 1, nxt = cur ^ 1;
    if (it < 15) {
      int m0 = (it + 1) * 64;
      gl_lds16(gK1 + (size_t)m0 * 64, &Ks[nxt][lo1]);
      gl_lds16(gK2 + (size_t)m0 * 64, &Ks[nxt][lo2]);
      gl_lds16(gV1 + m0, &Vs[nxt][lo1]);
      gl_lds16(gV2 + m0, &Vs[nxt][lo2]);
    }
    const uint16_t* Kc = Ks[cur];
    const uint16_t* Vc = Vs[cur];

    f32x4 sacc[2][4] = {};
#pragma unroll
    for (int mt = 0; mt < 4; mt++) {
      int row = mt * 16 + l15;
      int s0 = qd ^ (l15 & 7);
      bf16x8 kf0 = frag_ld(Kc + (size_t)row * 64 + s0 * 8);
      bf16x8 kf1 = frag_ld(Kc + (size_t)row * 64 + (s0 ^ 4) * 8);
#pragma unroll
      for (int rs = 0; rs < 2; rs++) {
        sacc[rs][mt] = MFMA16(kf0, qf[rs][0], sacc[rs][mt]);
        sacc[rs][mt] = MFMA16(kf1, qf[rs][1], sacc[rs][mt]);
      }
    }

#pragma unroll
    for (int rs = 0; rs < 2; rs++)
#pragma unroll
      for (int mt = 0; mt < 4; mt++) {
        union { uint16_t u[4]; uint2 v; } pk;
        float psum = 0.f;
#pragma unroll
        for (int r = 0; r < 4; r++) {
          float p = __expf(sacc[rs][mt][r]);
          psum += p;
          pk.u[r] = (uint16_t)(__builtin_bit_cast(uint32_t, p) >> 16);
        }
        lsum[rs] += psum;
        *(uint2*)(Ps + (size_t)(w * 32 + rs * 16 + l15) * 72 + mt * 16 + qd * 4) = pk.v;
      }

    bf16x8 pf[2][2];
#pragma unroll
    for (int rs = 0; rs < 2; rs++)
#pragma unroll
      for (int ks = 0; ks < 2; ks++)
        pf[rs][ks] = frag_ld(Ps + (size_t)(w * 32 + rs * 16 + l15) * 72 + ks * 32 + qd * 8);
#pragma unroll
    for (int dt = 0; dt < 4; dt++)
#pragma unroll
      for (int ks = 0; ks < 2; ks++) {
        int row = dt * 16 + l15;
        int slot = (ks * 4 + qd) ^ (l15 & 7);
        bf16x8 vf = frag_ld(Vc + (size_t)row * 64 + slot * 8);
#pragma unroll
        for (int rs = 0; rs < 2; rs++)
          oaccT[rs][dt] = MFMA16(vf, pf[rs][ks], oaccT[rs][dt]);
      }

    __syncthreads();
  }

#pragma unroll
  for (int rs = 0; rs < 2; rs++) {
    float s = lsum[rs];
    s += __shfl_xor(s, 16);
    s += __shfl_xor(s, 32);
    float rinv = 1.0f / s;
    int n = n0 + w * 32 + rs * 16 + l15;
    uint16_t* orow = ot + (size_t)b * 524288 + (size_t)n * 512 + h * 64;
#pragma unroll
    for (int dt = 0; dt < 4; dt++) {
      union { uint16_t u[4]; uint2 v; } pk;
#pragma unroll
      for (int r = 0; r < 4; r++) pk.u[r] = f2bf(oaccT[rs][dt][r] * rinv);
      *(uint2*)(orow + dt * 16 + qd * 4) = pk.v;
    }
  }
}

extern "C" void kernel_launch(void* const* d_in, const int* in_sizes, int n_in,
                              void* d_out, int out_size, void* d_ws, size_t ws_size,
                              hipStream_t stream) {
  (void)in_sizes; (void)n_in; (void)out_size; (void)ws_size;
  const float* xf   = (const float*)d_in[0];
  const float* gamf = (const float*)d_in[1];
  const float* betf = (const float*)d_in[2];
  const float* wqf  = (const float*)d_in[3];
  const float* wpf  = (const float*)d_in[4];
  const float* bprf = (const float*)d_in[5];
  float* out = (float*)d_out;

  uint16_t* base = (uint16_t*)d_ws;
  float* stats   = (float*)base;           // 512 floats (partial s1,s2 x 256)
  uint16_t* wqb  = base + 1024;
  uint16_t* wpb  = wqb + 786432;
  uint16_t* xn   = wpb + 262144;           // (B,N,C); reused as otw after gemm01
  uint16_t* qtw  = xn  + 4194304;          // (B,H,N,hd), Q pre-scaled by 1/8
  uint16_t* ktw  = qtw + 4194304;          // (B,H,N,hd)
  uint16_t* vtw  = ktw + 4194304;          // (B, h*64+d, N)
  uint16_t* otw  = xn;

  prep_k<<<768, 256, 0, stream>>>(wqf, wpf, wqb, wpb, xf, stats);
  gn_apply_k<<<dim3(16, 8, 8), 256, 0, stream>>>(xf, gamf, betf, stats, xn);
  gemm01_k<<<768, 256, 0, stream>>>(xn, wqb, qtw, ktw, vtw);
  attn_k<<<dim3(64, 8), 256, 0, stream>>>(qtw, ktw, vtw, otw);
  gemm2_k<<<256, 256, 0, stream>>>(wpb, otw, xf, bprf, out);
}